// Round 10
// baseline (1919.040 us; speedup 1.0000x reference)
//
#include <hip/hip_runtime.h>

typedef unsigned short u16;
typedef unsigned int u32;
typedef unsigned long long u64;
typedef __attribute__((ext_vector_type(8))) short short8;
typedef __attribute__((ext_vector_type(4))) float float4_t;
typedef __attribute__((ext_vector_type(2))) u32 u32x2;
typedef __attribute__((ext_vector_type(4))) u32 u32x4;

__device__ __forceinline__ u16 f2bf(float f) {
    union { float f; u32 u; } x; x.f = f;
    u32 r = x.u + 0x7FFFu + ((x.u >> 16) & 1u);
    return (u16)(r >> 16);
}
__device__ __forceinline__ float bitsf(u32 u) {
    union { u32 u; float f; } x; x.u = u; return x.f;
}
// pack two floats' (biased-rounded) bf16 into one u32: [hi:lo]
__device__ __forceinline__ u32 pk2bf(float hi, float lo) {
    union { float f; u32 u; } a, b; a.f = hi; b.f = lo;
    return __builtin_amdgcn_perm(a.u + 0x8000u, b.u + 0x8000u, 0x07060302u);
}
#define LOG2E 1.44269504088896340736f
__device__ __forceinline__ float tanh_(float x) {  // 1 - 2/(1+e^{2x})
    float t = __builtin_amdgcn_exp2f(2.f * LOG2E * x);
    return 1.f - 2.f * __builtin_amdgcn_rcpf(1.f + t);
}

__device__ __forceinline__ float4_t mfma16(short8 a, short8 b, float4_t c) {
    return __builtin_amdgcn_mfma_f32_16x16x32_bf16(a, b, c, 0, 0, 0);
}

// fragment loaders: 8 contiguous K-elements starting at p
__device__ __forceinline__ short8 ldfrag(const u16* p) { return *(const short8*)p; }
__device__ __forceinline__ short8 ldfrag(const float* p) {
    float4_t a = *(const float4_t*)p;
    float4_t b = *(const float4_t*)(p + 4);
    short8 r;
#pragma unroll
    for (int j = 0; j < 4; ++j) { r[j] = (short)f2bf(a[j]); r[4 + j] = (short)f2bf(b[j]); }
    return r;
}

// ---------------------------------------------------------------------------
// gemm_ih: Xih[M,512](bf16) = scale(col) * (A[M,128] @ W[512,128]^T + b1 + b2)
// Gate pre-activations pre-scaled: i,f,o cols get -log2e; g cols +2log2e.
// Block (0,0) also zeroes stats[0..256).
// ---------------------------------------------------------------------------
template<typename AT>
__global__ __launch_bounds__(256) void gemm_ih(
    const AT* __restrict__ A, const float* __restrict__ W,
    const float* __restrict__ b1, const float* __restrict__ b2,
    u16* __restrict__ C, float* __restrict__ stats, int M)
{
    if (blockIdx.x == 0 && blockIdx.y == 0) stats[threadIdx.x] = 0.f;
    const int P = 512;
    const int lane = threadIdx.x & 63;
    const int w    = threadIdx.x >> 6;
    const int l15  = lane & 15;
    const int quad = lane >> 4;
    const int rowbase = blockIdx.x * 64;
    const int colbase = blockIdx.y * 128 + w * 32;

    short8 af[4][4];
#pragma unroll
    for (int mb = 0; mb < 4; ++mb) {
        int row = rowbase + mb * 16 + l15;
        if (row >= M) row = M - 1;
        const AT* ap = A + (size_t)row * 128 + quad * 8;
#pragma unroll
        for (int kb = 0; kb < 4; ++kb) af[mb][kb] = ldfrag(ap + kb * 32);
    }
    short8 bfr[2][4];
#pragma unroll
    for (int nb = 0; nb < 2; ++nb) {
        int col = colbase + nb * 16 + l15;
        const float* wp = W + (size_t)col * 128 + quad * 8;
#pragma unroll
        for (int kb = 0; kb < 4; ++kb) bfr[nb][kb] = ldfrag(wp + kb * 32);
    }
    const float4_t z4 = {0.f, 0.f, 0.f, 0.f};
    float bias[2], scl[2];
#pragma unroll
    for (int nb = 0; nb < 2; ++nb) {
        int col = colbase + nb * 16 + l15;
        bias[nb] = b1[col] + b2[col];
        scl[nb] = (col >= 256 && col < 384) ? (2.f * LOG2E) : (-LOG2E);
    }
#pragma unroll
    for (int mb = 0; mb < 4; ++mb)
#pragma unroll
        for (int nb = 0; nb < 2; ++nb) {
            float4_t a = z4;
#pragma unroll
            for (int kb = 0; kb < 4; ++kb) a = mfma16(af[mb][kb], bfr[nb][kb], a);
#pragma unroll
            for (int r = 0; r < 4; ++r) {
                int row = rowbase + mb * 16 + quad * 4 + r;
                int col = colbase + nb * 16 + l15;
                if (row < M) C[(size_t)row * P + col] = f2bf((a[r] + bias[nb]) * scl[nb]);
            }
        }
}

// ---------------------------------------------------------------------------
// gemm_out: P[M,128](f32) = A1@W1^T + A2@W2^T + bias ; per-col sum/sumsq atomics
// ---------------------------------------------------------------------------
template<typename T>
__device__ __forceinline__ void accum_gemm(
    const T* __restrict__ A, const float* __restrict__ W,
    float4_t (&acc)[4][2], int M, int rowbase, int colbase, int l15, int quad)
{
    short8 af[4][4];
#pragma unroll
    for (int mb = 0; mb < 4; ++mb) {
        int row = rowbase + mb * 16 + l15;
        if (row >= M) row = M - 1;
        const T* ap = A + (size_t)row * 128 + quad * 8;
#pragma unroll
        for (int kb = 0; kb < 4; ++kb) af[mb][kb] = ldfrag(ap + kb * 32);
    }
    short8 bfr[2][4];
#pragma unroll
    for (int nb = 0; nb < 2; ++nb) {
        int col = colbase + nb * 16 + l15;
        const float* wp = W + (size_t)col * 128 + quad * 8;
#pragma unroll
        for (int kb = 0; kb < 4; ++kb) bfr[nb][kb] = ldfrag(wp + kb * 32);
    }
#pragma unroll
    for (int mb = 0; mb < 4; ++mb)
#pragma unroll
        for (int nb = 0; nb < 2; ++nb)
#pragma unroll
            for (int kb = 0; kb < 4; ++kb)
                acc[mb][nb] = mfma16(af[mb][kb], bfr[nb][kb], acc[mb][nb]);
}

template<typename AT2>
__global__ __launch_bounds__(256) void gemm_out(
    const u16* __restrict__ A1, const float* __restrict__ W1,
    const AT2* __restrict__ A2, const float* __restrict__ W2,
    const float* __restrict__ bias, float* __restrict__ C,
    float* __restrict__ stats, int M)
{
    const int P = 128;
    const int lane = threadIdx.x & 63;
    const int w    = threadIdx.x >> 6;
    const int l15  = lane & 15;
    const int quad = lane >> 4;
    const int rowbase = blockIdx.x * 64;
    const int colbase = w * 32;

    float4_t acc[4][2];
    const float4_t z4 = {0.f, 0.f, 0.f, 0.f};
#pragma unroll
    for (int mb = 0; mb < 4; ++mb)
#pragma unroll
        for (int nb = 0; nb < 2; ++nb) acc[mb][nb] = z4;

    accum_gemm(A1, W1, acc, M, rowbase, colbase, l15, quad);
    accum_gemm(A2, W2, acc, M, rowbase, colbase, l15, quad);

    float s[2] = {0.f, 0.f}, sq[2] = {0.f, 0.f};
#pragma unroll
    for (int nb = 0; nb < 2; ++nb) {
        int col = colbase + nb * 16 + l15;
        float bb = bias[col];
#pragma unroll
        for (int mb = 0; mb < 4; ++mb)
#pragma unroll
            for (int r = 0; r < 4; ++r) {
                int row = rowbase + mb * 16 + quad * 4 + r;
                if (row < M) {
                    float v = acc[mb][nb][r] + bb;
                    C[(size_t)row * P + col] = v;
                    s[nb] += v; sq[nb] += v * v;
                }
            }
    }
#pragma unroll
    for (int nb = 0; nb < 2; ++nb) {
        float t1 = s[nb], t2 = sq[nb];
        t1 += __shfl_xor(t1, 16); t1 += __shfl_xor(t1, 32);
        t2 += __shfl_xor(t2, 16); t2 += __shfl_xor(t2, 32);
        int col = colbase + nb * 16 + l15;
        if (quad == 0) atomicAdd(&stats[col], t1);
        if (quad == 1) atomicAdd(&stats[P + col], t2);
    }
}

// ---------------------------------------------------------------------------
// Barrier-free LSTM aggregator, wave-owns-nodes, 32 NODES/WAVE.
// 512 thr (8 waves), 256 nodes/block, wave w owns nodes base+32w..+31 (two
// 16-node MFMA n-tiles — each whs A-frag read feeds BOTH tiles, halving the
// per-node LDS cost vs the 16-node variant: round 9 measured the 8x-duplicated
// Whh read as the dominant pipe at 16 nodes/wave). Whh staged once in LDS
// (bf16, gate-pre-scaled, chunk c of row R at slot c^(R&15) -> b128 reads at
// the uniform 8-access/bank floor). h(t) in registers; quad-lane dim
// redistribution via wave-PRIVATE scr (in-order DS, no barrier). One
// __syncthreads total.
// Register regime: liveness ~230-250. Two proven guards make this fit:
// (a) amdgpu_waves_per_eu(2,2) — 2 waves/EU is the TRUE occupancy (144 KB
//     LDS -> 1 block/CU), lifting the backend's default 4-waves/EU 128-VGPR
//     cap to 256 (rounds 6/7 spilled 768 MB/dispatch under that cap);
// (b) sched_barrier(0) per dc iteration — stops cross-iteration gather-load
//     hoisting (round 9: held the 16-node variant to 92 VGPR, zero spill).
// WRITE_SIZE is the spill canary (~25-50 MB = clean; >>100 MB = revert).
// ---------------------------------------------------------------------------
__global__ __launch_bounds__(512, 1) __attribute__((amdgpu_waves_per_eu(2, 2)))
void lstm_kernel(
    const u16* __restrict__ Xih,   // [N,512] bf16, pre-scaled gate order i,f,g,o
    const int* __restrict__ nbr,   // [N,16]
    const float* __restrict__ Whh, // [512,128] f32 (scaled at staging)
    u16* __restrict__ Hout,        // [N,128] bf16
    int N)
{
    __shared__ u16 whs[512 * 128];     // 128 KB swizzled Whh (bf16)
    __shared__ u32 scr[8][32][16];     // 16 KB: per-wave h-redistribution scratch
    const int tid  = threadIdx.x;
    const int lane = tid & 63;
    const int w    = tid >> 6;           // wave 0..7
    const int l15  = lane & 15;
    const int quad = lane >> 4;
    const int base = blockIdx.x * 256;

    // ---- stage Whh -> LDS: bf16, gate-scaled, chunk-swizzled (coalesced) ----
    for (int i = tid; i < 512 * 16; i += 512) {
        const int R = i >> 4, cch = i & 15;
        const float s = ((R >> 7) == 2) ? (2.f * LOG2E) : (-LOG2E);
        const float* wp = Whh + (size_t)R * 128 + cch * 8;
        float4_t a = *(const float4_t*)wp;
        float4_t b = *(const float4_t*)(wp + 4);
        u32x4 pk;
        pk[0] = ((u32)f2bf(a[1] * s) << 16) | f2bf(a[0] * s);
        pk[1] = ((u32)f2bf(a[3] * s) << 16) | f2bf(a[2] * s);
        pk[2] = ((u32)f2bf(b[1] * s) << 16) | f2bf(b[0] * s);
        pk[3] = ((u32)f2bf(b[3] * s) << 16) | f2bf(b[2] * s);
        *(u32x4*)&whs[R * 128 + ((cch ^ (R & 15)) << 3)] = pk;
    }
    __syncthreads();

    // owners (clamped for tail block)
    const int own0s = base + w * 32 + l15;
    const int own1s = own0s + 16;
    const int own0 = own0s < N ? own0s : N - 1;
    const int own1 = own1s < N ? own1s : N - 1;

    int xcur0 = nbr[(size_t)own0 * 16];
    int xcur1 = nbr[(size_t)own1 * 16];

    const float4_t z4 = {0.f, 0.f, 0.f, 0.f};
    float4_t c[8][2];
#pragma unroll
    for (int dc = 0; dc < 8; ++dc) { c[dc][0] = z4; c[dc][1] = z4; }
    const short8 zs8 = {0, 0, 0, 0, 0, 0, 0, 0};
    short8 hfA[2][4];
#pragma unroll
    for (int n = 0; n < 2; ++n)
#pragma unroll
        for (int kb = 0; kb < 4; ++kb) hfA[n][kb] = zs8;

    for (int t = 0; t < 16; ++t) {
        int xn0 = 0, xn1 = 0;
        if (t < 15) {   // prefetch next step's neighbor ids (L2-resident table)
            xn0 = nbr[(size_t)own0 * 16 + t + 1];
            xn1 = nbr[(size_t)own1 * 16 + t + 1];
        }
        const u16* bp0 = Xih + (size_t)xcur0 * 512 + 4 * quad;
        const u16* bp1 = Xih + (size_t)xcur1 * 512 + 4 * quad;

        u32x2 gb[2][2][4];   // [parity][n][gate] gather pipeline, 1 dc ahead
#pragma unroll
        for (int g = 0; g < 4; ++g) {
            gb[0][0][g] = *(const u32x2*)(bp0 + 128 * g);
            gb[0][1][g] = *(const u32x2*)(bp1 + 128 * g);
        }
        short8 hfB[2][4];
#pragma unroll
        for (int dc = 0; dc < 8; ++dc) {
            const int par = dc & 1;
            if (dc < 7) {
#pragma unroll
                for (int g = 0; g < 4; ++g) {
                    gb[par ^ 1][0][g] = *(const u32x2*)(bp0 + 128 * g + 16 * (dc + 1));
                    gb[par ^ 1][1][g] = *(const u32x2*)(bp1 + 128 * g + 16 * (dc + 1));
                }
            }
            // z init from gathered Xih (accumulator layout: dims 16dc+4q+r)
            float4_t z[4][2];
#pragma unroll
            for (int g = 0; g < 4; ++g)
#pragma unroll
                for (int n = 0; n < 2; ++n) {
                    u32 w0 = gb[par][n][g][0], w1 = gb[par][n][g][1];
                    z[g][n][0] = bitsf(w0 << 16); z[g][n][1] = bitsf(w0 & 0xFFFF0000u);
                    z[g][n][2] = bitsf(w1 << 16); z[g][n][3] = bitsf(w1 & 0xFFFF0000u);
                }
            // recurrent GEMM: A-frag loaded once per (kb,g), reused for BOTH n
#pragma unroll
            for (int kb = 0; kb < 4; ++kb)
#pragma unroll
                for (int g = 0; g < 4; ++g) {
                    const short8 whf = *(const short8*)&whs[
                        (128 * g + 16 * dc + l15) * 128 +
                        ((((kb << 2) | quad) ^ l15) << 3)];
                    z[g][0] = mfma16(whf, hfA[0][kb], z[g][0]);
                    z[g][1] = mfma16(whf, hfA[1][kb], z[g][1]);
                }
            // gates (pre-scaled domain), cell update, h pack
#pragma unroll
            for (int n = 0; n < 2; ++n) {
                float4_t hv;
#pragma unroll
                for (int r = 0; r < 4; ++r) {
                    float i_ = __builtin_amdgcn_rcpf(1.f + __builtin_amdgcn_exp2f(z[0][n][r]));
                    float f_ = __builtin_amdgcn_rcpf(1.f + __builtin_amdgcn_exp2f(z[1][n][r]));
                    float g_ = 1.f - 2.f * __builtin_amdgcn_rcpf(1.f + __builtin_amdgcn_exp2f(z[2][n][r]));
                    float o_ = __builtin_amdgcn_rcpf(1.f + __builtin_amdgcn_exp2f(z[3][n][r]));
                    float cc = f_ * c[dc][n][r] + i_ * g_;
                    c[dc][n][r] = cc;
                    hv[r] = o_ * tanh_(cc);
                }
                u32x2 pr;
                pr[0] = pk2bf(hv[1], hv[0]);
                pr[1] = pk2bf(hv[3], hv[2]);
                if (t < 15) {
                    // wave-private scr, B-frag slot for dims kl=16*par+4q+{0..3}
                    *(u32x2*)&scr[w][n * 16 + l15][8 * par + 2 * quad] = pr;
                } else {
                    const int own = n ? own1s : own0s;
                    if (own < N)
                        *(u32x2*)(Hout + (size_t)own * 128 + 16 * dc + 4 * quad) = pr;
                }
            }
            // after each dc pair, read back the completed kb-frag (in-order DS)
            if (par && t < 15) {
                const int kb = dc >> 1;
                hfB[0][kb] = *(const short8*)&scr[w][l15][4 * quad];
                hfB[1][kb] = *(const short8*)&scr[w][16 + l15][4 * quad];
            }
            // fence: no cross-iteration load hoisting (liveness control)
            __builtin_amdgcn_sched_barrier(0);
        }
        if (t < 15) {
#pragma unroll
            for (int n = 0; n < 2; ++n)
#pragma unroll
                for (int kb = 0; kb < 4; ++kb) hfA[n][kb] = hfB[n][kb];
            xcur0 = xn0; xcur1 = xn1;
        }
    }
}

// ---------------------------------------------------------------------------
__global__ void bn_prep(float* stats, const float* __restrict__ gamma,
                        const float* __restrict__ beta, float invN)
{
    int cidx = threadIdx.x;   // 0..127
    float s = stats[cidx], sq = stats[128 + cidx];
    float mu = s * invN;
    float var = sq * invN - mu * mu;
    float sc = gamma[cidx] * rsqrtf(var + 1e-5f);
    stats[256 + cidx] = sc;
    stats[384 + cidx] = beta[cidx] - mu * sc;
}

template<typename OT>
__global__ __launch_bounds__(256) void bn_apply(
    const float* __restrict__ X, const float* __restrict__ stats,
    OT* __restrict__ Y, int M, int relu)
{
    int gid = blockIdx.x * 256 + threadIdx.x;
    int row = gid >> 4;
    int cs  = (gid & 15) * 8;
    if (row >= M) return;
    float4_t a = *(const float4_t*)(X + (size_t)row * 128 + cs);
    float4_t b = *(const float4_t*)(X + (size_t)row * 128 + cs + 4);
    float v[8];
#pragma unroll
    for (int j = 0; j < 8; ++j) {
        float x = (j < 4) ? a[j] : b[j - 4];
        float t = x * stats[256 + cs + j] + stats[384 + cs + j];
        v[j] = relu ? fmaxf(t, 0.f) : t;
    }
    if constexpr (sizeof(OT) == 2) {
        short8 ov;
#pragma unroll
        for (int j = 0; j < 8; ++j) ov[j] = (short)f2bf(v[j]);
        *(short8*)((u16*)Y + (size_t)row * 128 + cs) = ov;
    } else {
        float4_t o1, o2;
#pragma unroll
        for (int j = 0; j < 4; ++j) { o1[j] = v[j]; o2[j] = v[4 + j]; }
        *(float4_t*)((float*)Y + (size_t)row * 128 + cs) = o1;
        *(float4_t*)((float*)Y + (size_t)row * 128 + cs + 4) = o2;
    }
}

// ---------------------------------------------------------------------------
extern "C" void kernel_launch(void* const* d_in, const int* in_sizes, int n_in,
                              void* d_out, int out_size, void* d_ws, size_t ws_size,
                              hipStream_t stream)
{
    const float* in_feat = (const float*)d_in[0];
    const int*   nbr     = (const int*)d_in[1];
    const float* Wih1 = (const float*)d_in[2];
    const float* Whh1 = (const float*)d_in[3];
    const float* bih1 = (const float*)d_in[4];
    const float* bhh1 = (const float*)d_in[5];
    const float* Wself1  = (const float*)d_in[6];
    const float* bself1  = (const float*)d_in[7];
    const float* Wneigh1 = (const float*)d_in[8];
    const float* gamma1  = (const float*)d_in[9];
    const float* beta1   = (const float*)d_in[10];
    const float* Wih2 = (const float*)d_in[11];
    const float* Whh2 = (const float*)d_in[12];
    const float* bih2 = (const float*)d_in[13];
    const float* bhh2 = (const float*)d_in[14];
    const float* Wself2  = (const float*)d_in[15];
    const float* bself2  = (const float*)d_in[16];
    const float* Wneigh2 = (const float*)d_in[17];
    const float* gamma2  = (const float*)d_in[18];
    const float* beta2   = (const float*)d_in[19];

    const int N = in_sizes[0] / 128;

    char* ws = (char*)d_ws;
    u16*   Xih   = (u16*)ws;                       // [N,512] bf16 (aliases Pbuf)
    float* Pbuf  = (float*)ws;                     // [N,128] f32
    u16*   hn    = (u16*)(ws + (size_t)N * 1024);  // [N,128] bf16
    float* stats = (float*)(ws + (size_t)N * 1024 + (size_t)N * 256);
    u16*   hcur  = (u16*)d_out;                    // bf16 scratch inside d_out

    const int nblk = (N + 63) / 64;
    const int lblk = (N + 255) / 256;
    const float invN = 1.0f / (float)N;
    const int bnblk = (N * 16 + 255) / 256;

    // ---------------- layer 1 ----------------
    gemm_ih<float><<<dim3(nblk, 4), dim3(256), 0, stream>>>(in_feat, Wih1, bih1, bhh1, Xih, stats, N);
    lstm_kernel<<<dim3(lblk), dim3(512), 0, stream>>>(Xih, nbr, Whh1, hn, N);
    gemm_out<float><<<dim3(nblk, 1), dim3(256), 0, stream>>>(hn, Wneigh1, in_feat, Wself1,
                                                             bself1, Pbuf, stats, N);
    bn_prep<<<dim3(1), dim3(128), 0, stream>>>(stats, gamma1, beta1, invN);
    bn_apply<u16><<<dim3(bnblk), dim3(256), 0, stream>>>(Pbuf, stats, hcur, N, 1);

    // ---------------- layer 2 ----------------
    gemm_ih<u16><<<dim3(nblk, 4), dim3(256), 0, stream>>>(hcur, Wih2, bih2, bhh2, Xih, stats, N);
    lstm_kernel<<<dim3(lblk), dim3(512), 0, stream>>>(Xih, nbr, Whh2, hn, N);
    gemm_out<u16><<<dim3(nblk, 1), dim3(256), 0, stream>>>(hn, Wneigh2, hcur, Wself2,
                                                           bself2, Pbuf, stats, N);
    bn_prep<<<dim3(1), dim3(128), 0, stream>>>(stats, gamma2, beta2, invN);
    bn_apply<float><<<dim3(bnblk), dim3(256), 0, stream>>>(Pbuf, stats, (float*)d_out, N, 0);
}

// Round 11
// 1605.678 us; speedup vs baseline: 1.1952x; 1.1952x over previous
//
#include <hip/hip_runtime.h>

typedef unsigned short u16;
typedef unsigned int u32;
typedef unsigned long long u64;
typedef __attribute__((ext_vector_type(8))) short short8;
typedef __attribute__((ext_vector_type(4))) float float4_t;
typedef __attribute__((ext_vector_type(2))) u32 u32x2;

__device__ __forceinline__ u16 f2bf(float f) {
    union { float f; u32 u; } x; x.f = f;
    u32 r = x.u + 0x7FFFu + ((x.u >> 16) & 1u);
    return (u16)(r >> 16);
}
__device__ __forceinline__ float bitsf(u32 u) {
    union { u32 u; float f; } x; x.u = u; return x.f;
}
// pack two floats' (biased-rounded) bf16 into one u32: [hi:lo]
__device__ __forceinline__ u32 pk2bf(float hi, float lo) {
    union { float f; u32 u; } a, b; a.f = hi; b.f = lo;
    return __builtin_amdgcn_perm(a.u + 0x8000u, b.u + 0x8000u, 0x07060302u);
}
#define LOG2E 1.44269504088896340736f
__device__ __forceinline__ float tanh_(float x) {  // 1 - 2/(1+e^{2x})
    float t = __builtin_amdgcn_exp2f(2.f * LOG2E * x);
    return 1.f - 2.f * __builtin_amdgcn_rcpf(1.f + t);
}

__device__ __forceinline__ float4_t mfma16(short8 a, short8 b, float4_t c) {
    return __builtin_amdgcn_mfma_f32_16x16x32_bf16(a, b, c, 0, 0, 0);
}

// barrier that does NOT drain vmcnt: LDS ordering only. Gather prefetches
// stay in flight across the step boundary (compiler still inserts correct
// vmcnt waits at their consumption points). [round 4: 607 -> 530 us]
#define LDS_BARRIER() asm volatile("s_waitcnt lgkmcnt(0)\n\ts_barrier" ::: "memory")

// fragment loaders: 8 contiguous K-elements starting at p
__device__ __forceinline__ short8 ldfrag(const u16* p) { return *(const short8*)p; }
__device__ __forceinline__ short8 ldfrag(const float* p) {
    float4_t a = *(const float4_t*)p;
    float4_t b = *(const float4_t*)(p + 4);
    short8 r;
#pragma unroll
    for (int j = 0; j < 4; ++j) { r[j] = (short)f2bf(a[j]); r[4 + j] = (short)f2bf(b[j]); }
    return r;
}
__device__ __forceinline__ short8 ldfrag_scaled(const float* p, float s) {
    float4_t a = *(const float4_t*)p;
    float4_t b = *(const float4_t*)(p + 4);
    short8 r;
#pragma unroll
    for (int j = 0; j < 4; ++j) { r[j] = (short)f2bf(a[j] * s); r[4 + j] = (short)f2bf(b[j] * s); }
    return r;
}
// bn+relu fused loader: r[j] = bf16(max(p[j]*sc[j]+sh[j], 0)) — bit-identical
// to the old bn_apply<u16> pass (same f32 math, same f2bf rounding).
__device__ __forceinline__ short8 ldfrag_bnrelu(
    const float* p, const float* sc, const float* sh)
{
    float4_t a = *(const float4_t*)p,       b = *(const float4_t*)(p + 4);
    float4_t s1 = *(const float4_t*)sc,     s2 = *(const float4_t*)(sc + 4);
    float4_t h1 = *(const float4_t*)sh,     h2 = *(const float4_t*)(sh + 4);
    short8 r;
#pragma unroll
    for (int j = 0; j < 4; ++j) {
        r[j]     = (short)f2bf(fmaxf(a[j] * s1[j] + h1[j], 0.f));
        r[4 + j] = (short)f2bf(fmaxf(b[j] * s2[j] + h2[j], 0.f));
    }
    return r;
}

// ---------------------------------------------------------------------------
// gemm_ih: Xih[M,512](bf16) = scale(col) * (A[M,128] @ W[512,128]^T + b1 + b2)
// Gate pre-activations pre-scaled: i,f,o cols get -log2e; g cols +2log2e.
// Block (0,0) also zeroes stats[0..256).
// ---------------------------------------------------------------------------
template<typename AT>
__global__ __launch_bounds__(256) void gemm_ih(
    const AT* __restrict__ A, const float* __restrict__ W,
    const float* __restrict__ b1, const float* __restrict__ b2,
    u16* __restrict__ C, float* __restrict__ stats, int M)
{
    if (blockIdx.x == 0 && blockIdx.y == 0) stats[threadIdx.x] = 0.f;
    const int P = 512;
    const int lane = threadIdx.x & 63;
    const int w    = threadIdx.x >> 6;
    const int l15  = lane & 15;
    const int quad = lane >> 4;
    const int rowbase = blockIdx.x * 64;
    const int colbase = blockIdx.y * 128 + w * 32;

    short8 af[4][4];
#pragma unroll
    for (int mb = 0; mb < 4; ++mb) {
        int row = rowbase + mb * 16 + l15;
        if (row >= M) row = M - 1;
        const AT* ap = A + (size_t)row * 128 + quad * 8;
#pragma unroll
        for (int kb = 0; kb < 4; ++kb) af[mb][kb] = ldfrag(ap + kb * 32);
    }
    short8 bfr[2][4];
#pragma unroll
    for (int nb = 0; nb < 2; ++nb) {
        int col = colbase + nb * 16 + l15;
        const float* wp = W + (size_t)col * 128 + quad * 8;
#pragma unroll
        for (int kb = 0; kb < 4; ++kb) bfr[nb][kb] = ldfrag(wp + kb * 32);
    }
    const float4_t z4 = {0.f, 0.f, 0.f, 0.f};
    float bias[2], scl[2];
#pragma unroll
    for (int nb = 0; nb < 2; ++nb) {
        int col = colbase + nb * 16 + l15;
        bias[nb] = b1[col] + b2[col];
        scl[nb] = (col >= 256 && col < 384) ? (2.f * LOG2E) : (-LOG2E);
    }
#pragma unroll
    for (int mb = 0; mb < 4; ++mb)
#pragma unroll
        for (int nb = 0; nb < 2; ++nb) {
            float4_t a = z4;
#pragma unroll
            for (int kb = 0; kb < 4; ++kb) a = mfma16(af[mb][kb], bfr[nb][kb], a);
#pragma unroll
            for (int r = 0; r < 4; ++r) {
                int row = rowbase + mb * 16 + quad * 4 + r;
                int col = colbase + nb * 16 + l15;
                if (row < M) C[(size_t)row * P + col] = f2bf((a[r] + bias[nb]) * scl[nb]);
            }
        }
}

// Layer-2 variant: A = P1 (f32) with fused bn+relu from stats[256..512).
// Writes to stats[0..256) (the zeroing) are disjoint from those reads.
__global__ __launch_bounds__(256) void gemm_ih_bn(
    const float* __restrict__ A, const float* __restrict__ W,
    const float* __restrict__ b1, const float* __restrict__ b2,
    u16* __restrict__ C, float* __restrict__ stats, int M)
{
    if (blockIdx.x == 0 && blockIdx.y == 0) stats[threadIdx.x] = 0.f;
    const int P = 512;
    const int lane = threadIdx.x & 63;
    const int w    = threadIdx.x >> 6;
    const int l15  = lane & 15;
    const int quad = lane >> 4;
    const int rowbase = blockIdx.x * 64;
    const int colbase = blockIdx.y * 128 + w * 32;

    short8 af[4][4];
#pragma unroll
    for (int mb = 0; mb < 4; ++mb) {
        int row = rowbase + mb * 16 + l15;
        if (row >= M) row = M - 1;
        const float* ap = A + (size_t)row * 128 + quad * 8;
#pragma unroll
        for (int kb = 0; kb < 4; ++kb)
            af[mb][kb] = ldfrag_bnrelu(ap + kb * 32,
                                       stats + 256 + quad * 8 + kb * 32,
                                       stats + 384 + quad * 8 + kb * 32);
    }
    short8 bfr[2][4];
#pragma unroll
    for (int nb = 0; nb < 2; ++nb) {
        int col = colbase + nb * 16 + l15;
        const float* wp = W + (size_t)col * 128 + quad * 8;
#pragma unroll
        for (int kb = 0; kb < 4; ++kb) bfr[nb][kb] = ldfrag(wp + kb * 32);
    }
    const float4_t z4 = {0.f, 0.f, 0.f, 0.f};
    float bias[2], scl[2];
#pragma unroll
    for (int nb = 0; nb < 2; ++nb) {
        int col = colbase + nb * 16 + l15;
        bias[nb] = b1[col] + b2[col];
        scl[nb] = (col >= 256 && col < 384) ? (2.f * LOG2E) : (-LOG2E);
    }
#pragma unroll
    for (int mb = 0; mb < 4; ++mb)
#pragma unroll
        for (int nb = 0; nb < 2; ++nb) {
            float4_t a = z4;
#pragma unroll
            for (int kb = 0; kb < 4; ++kb) a = mfma16(af[mb][kb], bfr[nb][kb], a);
#pragma unroll
            for (int r = 0; r < 4; ++r) {
                int row = rowbase + mb * 16 + quad * 4 + r;
                int col = colbase + nb * 16 + l15;
                if (row < M) C[(size_t)row * P + col] = f2bf((a[r] + bias[nb]) * scl[nb]);
            }
        }
}

// ---------------------------------------------------------------------------
// gemm_out: P[M,128](f32) = A1@W1^T + A2@W2^T + bias ; per-col sum/sumsq atomics
// ---------------------------------------------------------------------------
template<typename T>
__device__ __forceinline__ void accum_gemm(
    const T* __restrict__ A, const float* __restrict__ W,
    float4_t (&acc)[4][2], int M, int rowbase, int colbase, int l15, int quad)
{
    short8 af[4][4];
#pragma unroll
    for (int mb = 0; mb < 4; ++mb) {
        int row = rowbase + mb * 16 + l15;
        if (row >= M) row = M - 1;
        const T* ap = A + (size_t)row * 128 + quad * 8;
#pragma unroll
        for (int kb = 0; kb < 4; ++kb) af[mb][kb] = ldfrag(ap + kb * 32);
    }
    short8 bfr[2][4];
#pragma unroll
    for (int nb = 0; nb < 2; ++nb) {
        int col = colbase + nb * 16 + l15;
        const float* wp = W + (size_t)col * 128 + quad * 8;
#pragma unroll
        for (int kb = 0; kb < 4; ++kb) bfr[nb][kb] = ldfrag(wp + kb * 32);
    }
#pragma unroll
    for (int mb = 0; mb < 4; ++mb)
#pragma unroll
        for (int nb = 0; nb < 2; ++nb)
#pragma unroll
            for (int kb = 0; kb < 4; ++kb)
                acc[mb][nb] = mfma16(af[mb][kb], bfr[nb][kb], acc[mb][nb]);
}

// A with fused bn+relu (layer-2's self path reading P1)
__device__ __forceinline__ void accum_gemm_bn(
    const float* __restrict__ A, const float* __restrict__ stats,
    const float* __restrict__ W,
    float4_t (&acc)[4][2], int M, int rowbase, int colbase, int l15, int quad)
{
    short8 af[4][4];
#pragma unroll
    for (int mb = 0; mb < 4; ++mb) {
        int row = rowbase + mb * 16 + l15;
        if (row >= M) row = M - 1;
        const float* ap = A + (size_t)row * 128 + quad * 8;
#pragma unroll
        for (int kb = 0; kb < 4; ++kb)
            af[mb][kb] = ldfrag_bnrelu(ap + kb * 32,
                                       stats + 256 + quad * 8 + kb * 32,
                                       stats + 384 + quad * 8 + kb * 32);
    }
    short8 bfr[2][4];
#pragma unroll
    for (int nb = 0; nb < 2; ++nb) {
        int col = colbase + nb * 16 + l15;
        const float* wp = W + (size_t)col * 128 + quad * 8;
#pragma unroll
        for (int kb = 0; kb < 4; ++kb) bfr[nb][kb] = ldfrag(wp + kb * 32);
    }
#pragma unroll
    for (int mb = 0; mb < 4; ++mb)
#pragma unroll
        for (int nb = 0; nb < 2; ++nb)
#pragma unroll
            for (int kb = 0; kb < 4; ++kb)
                acc[mb][nb] = mfma16(af[mb][kb], bfr[nb][kb], acc[mb][nb]);
}

template<typename AT2>
__global__ __launch_bounds__(256) void gemm_out(
    const u16* __restrict__ A1, const float* __restrict__ W1,
    const AT2* __restrict__ A2, const float* __restrict__ W2,
    const float* __restrict__ bias, float* __restrict__ C,
    float* __restrict__ stats, int M)
{
    const int P = 128;
    const int lane = threadIdx.x & 63;
    const int w    = threadIdx.x >> 6;
    const int l15  = lane & 15;
    const int quad = lane >> 4;
    const int rowbase = blockIdx.x * 64;
    const int colbase = w * 32;

    float4_t acc[4][2];
    const float4_t z4 = {0.f, 0.f, 0.f, 0.f};
#pragma unroll
    for (int mb = 0; mb < 4; ++mb)
#pragma unroll
        for (int nb = 0; nb < 2; ++nb) acc[mb][nb] = z4;

    accum_gemm(A1, W1, acc, M, rowbase, colbase, l15, quad);
    accum_gemm(A2, W2, acc, M, rowbase, colbase, l15, quad);

    float s[2] = {0.f, 0.f}, sq[2] = {0.f, 0.f};
#pragma unroll
    for (int nb = 0; nb < 2; ++nb) {
        int col = colbase + nb * 16 + l15;
        float bb = bias[col];
#pragma unroll
        for (int mb = 0; mb < 4; ++mb)
#pragma unroll
            for (int r = 0; r < 4; ++r) {
                int row = rowbase + mb * 16 + quad * 4 + r;
                if (row < M) {
                    float v = acc[mb][nb][r] + bb;
                    C[(size_t)row * P + col] = v;
                    s[nb] += v; sq[nb] += v * v;
                }
            }
    }
#pragma unroll
    for (int nb = 0; nb < 2; ++nb) {
        float t1 = s[nb], t2 = sq[nb];
        t1 += __shfl_xor(t1, 16); t1 += __shfl_xor(t1, 32);
        t2 += __shfl_xor(t2, 16); t2 += __shfl_xor(t2, 32);
        int col = colbase + nb * 16 + l15;
        if (quad == 0) atomicAdd(&stats[col], t1);
        if (quad == 1) atomicAdd(&stats[P + col], t2);
    }
}

// Layer-2 variant: A2 = P1 (f32) with fused bn+relu; C written to a DISJOINT
// buffer (ws base — Xih is dead after lstm2), so no in-place hazards.
__global__ __launch_bounds__(256) void gemm_out_bn(
    const u16* __restrict__ A1, const float* __restrict__ W1,
    const float* __restrict__ A2, const float* __restrict__ W2,
    const float* __restrict__ bias, float* __restrict__ C,
    float* __restrict__ stats, int M)
{
    const int P = 128;
    const int lane = threadIdx.x & 63;
    const int w    = threadIdx.x >> 6;
    const int l15  = lane & 15;
    const int quad = lane >> 4;
    const int rowbase = blockIdx.x * 64;
    const int colbase = w * 32;

    float4_t acc[4][2];
    const float4_t z4 = {0.f, 0.f, 0.f, 0.f};
#pragma unroll
    for (int mb = 0; mb < 4; ++mb)
#pragma unroll
        for (int nb = 0; nb < 2; ++nb) acc[mb][nb] = z4;

    accum_gemm(A1, W1, acc, M, rowbase, colbase, l15, quad);
    accum_gemm_bn(A2, stats, W2, acc, M, rowbase, colbase, l15, quad);

    float s[2] = {0.f, 0.f}, sq[2] = {0.f, 0.f};
#pragma unroll
    for (int nb = 0; nb < 2; ++nb) {
        int col = colbase + nb * 16 + l15;
        float bb = bias[col];
#pragma unroll
        for (int mb = 0; mb < 4; ++mb)
#pragma unroll
            for (int r = 0; r < 4; ++r) {
                int row = rowbase + mb * 16 + quad * 4 + r;
                if (row < M) {
                    float v = acc[mb][nb][r] + bb;
                    C[(size_t)row * P + col] = v;
                    s[nb] += v; sq[nb] += v * v;
                }
            }
    }
#pragma unroll
    for (int nb = 0; nb < 2; ++nb) {
        float t1 = s[nb], t2 = sq[nb];
        t1 += __shfl_xor(t1, 16); t1 += __shfl_xor(t1, 32);
        t2 += __shfl_xor(t2, 16); t2 += __shfl_xor(t2, 32);
        int col = colbase + nb * 16 + l15;
        if (quad == 0) atomicAdd(&stats[col], t1);
        if (quad == 1) atomicAdd(&stats[P + col], t2);
    }
}

// ---------------------------------------------------------------------------
// Persistent LSTM aggregator — EXACT round-4 version (1538 us total, lstm 530):
// transposed z^T = Whh*h^T + Xih^T; 512 thr, 64 nodes/block, 16 steps; wave w
// owns dim-slice [16w,16w+16) of each gate; direct-gathered z init; gate
// pre-scaling; XOR-swizzled hbuf; LDS_BARRIER (no vmcnt drain); setprio(1)
// around MFMA cluster; direct Hout write at t=15. __launch_bounds__(512,2):
// 2nd arg = min BLOCKS/CU here; 128-VGPR budget, no spill (VGPR~100).
// [Rounds 5-10 post-mortem: 3 blocks/CU blocked by the 8-VGPR HW granule
// (84->88, 512/88=5 waves); barrier-free restructure blocked by a hard 128
// arch-VGPR ceiling for MFMA kernels on this toolchain. This structure is
// the register-local optimum.]
// ---------------------------------------------------------------------------
__global__ __launch_bounds__(512, 2) void lstm_kernel(
    const u16* __restrict__ Xih,   // [N,512] bf16, pre-scaled gate order i,f,g,o
    const int* __restrict__ nbr,   // [N,16]
    const float* __restrict__ Whh, // [512,128] f32 (unscaled; scaled at frag load)
    u16* __restrict__ Hout,        // [N,128] bf16
    int N)
{
    __shared__ u16 hbuf[2][64][128];
    __shared__ int nbrs[16][72];   // [step][node], padded
    const int tid  = threadIdx.x;
    const int lane = tid & 63;
    const int w    = tid >> 6;           // wave 0..7
    const int l15  = lane & 15;
    const int quad = lane >> 4;
    const int base = blockIdx.x * 64;

    // Whh A-fragments (register-resident): rows = output dims 128g+16w+l15,
    // pre-scaled per gate (g==2 is the tanh gate).
    short8 whA[4][4];
#pragma unroll
    for (int g = 0; g < 4; ++g) {
        int row = 128 * g + 16 * w + l15;
        float s = (g == 2) ? (2.f * LOG2E) : (-LOG2E);
        const float* wp = Whh + (size_t)row * 128 + quad * 8;
#pragma unroll
        for (int kb = 0; kb < 4; ++kb) whA[g][kb] = ldfrag_scaled(wp + kb * 32, s);
    }
    // zero both h buffers; stage neighbor indices (coalesced global reads)
    u32* hz = (u32*)&hbuf[0][0][0];
    for (int i = tid; i < 2 * 64 * 128 / 2; i += 512) hz[i] = 0u;
    for (int i = tid; i < 64 * 16; i += 512) {
        int node = base + (i >> 4);
        if (node >= N) node = N - 1;
        nbrs[i & 15][i >> 4] = nbr[(size_t)node * 16 + (i & 15)];
    }
    __syncthreads();

    // gather layout: lane (l15,quad) of wave w needs Xih[node][128g+16w+4q .. +3]
    const int xoff = 16 * w + 4 * quad;      // u16 units within each 128-col gate block

    // prefetch step 0 gather
    u32x2 xfu[4][4];                          // [nb][g]
#pragma unroll
    for (int nb = 0; nb < 4; ++nb) {
        int node = nbrs[0][l15 + 16 * nb];
        const u16* xp = Xih + (size_t)node * 512 + xoff;
#pragma unroll
        for (int g = 0; g < 4; ++g) xfu[nb][g] = *(const u32x2*)(xp + 128 * g);
    }

    const float4_t z4 = {0.f, 0.f, 0.f, 0.f};
    float4_t c[4];
#pragma unroll
    for (int nb = 0; nb < 4; ++nb) c[nb] = z4;

    for (int t = 0; t < 16; ++t) {
        const int p = t & 1;
#pragma unroll
        for (int nb = 0; nb < 4; ++nb) {
            const int row = l15 + 16 * nb;
            // init accumulators directly from gathered Xih (consumes xfu[nb])
            float4_t z[4];
#pragma unroll
            for (int g = 0; g < 4; ++g) {
                u32 w0 = xfu[nb][g][0], w1 = xfu[nb][g][1];
                z[g][0] = bitsf(w0 << 16); z[g][1] = bitsf(w0 & 0xFFFF0000u);
                z[g][2] = bitsf(w1 << 16); z[g][3] = bitsf(w1 & 0xFFFF0000u);
            }
            // prefetch next step's gather into xfu[nb] (WAR-safe: consumed above)
            if (t < 15) {
                int node = nbrs[t + 1][row];
                const u16* xp = Xih + (size_t)node * 512 + xoff;
#pragma unroll
                for (int g = 0; g < 4; ++g) xfu[nb][g] = *(const u32x2*)(xp + 128 * g);
            }
            // recurrent GEMM: one h(t-1) B-frag per kb (XOR-swizzled), 4 MFMAs
            const char* hrow = (const char*)&hbuf[p][row][0];
            __builtin_amdgcn_s_setprio(1);
#pragma unroll
            for (int kb = 0; kb < 4; ++kb) {
                int ch = (quad + 4 * kb) ^ (row & 7);
                short8 hb = *(const short8*)(hrow + (ch << 4));
#pragma unroll
                for (int g = 0; g < 4; ++g)
                    z[g] = mfma16(whA[g][kb], hb, z[g]);
            }
            __builtin_amdgcn_s_setprio(0);
            // gates: z pre-scaled so i,f,o = rcp(1+exp2(z)), g = 1-2*rcp(1+exp2(z))
            float4_t hv;
#pragma unroll
            for (int r = 0; r < 4; ++r) {
                float i_ = __builtin_amdgcn_rcpf(1.f + __builtin_amdgcn_exp2f(z[0][r]));
                float f_ = __builtin_amdgcn_rcpf(1.f + __builtin_amdgcn_exp2f(z[1][r]));
                float g_ = 1.f - 2.f * __builtin_amdgcn_rcpf(1.f + __builtin_amdgcn_exp2f(z[2][r]));
                float o_ = __builtin_amdgcn_rcpf(1.f + __builtin_amdgcn_exp2f(z[3][r]));
                float cc = f_ * c[nb][r] + i_ * g_;
                c[nb][r] = cc;
                hv[r] = o_ * tanh_(cc);
            }
            // packed h: 4 contiguous bf16 dims -> one b64 write
            u64 pkd = ((u64)pk2bf(hv[3], hv[2]) << 32) | pk2bf(hv[1], hv[0]);
            if (t < 15) {
                int ch = (2 * w + (quad >> 1)) ^ (row & 7);
                int sw = (ch << 4) | ((quad & 1) << 3);
                *(u64*)((char*)&hbuf[1 - p][row][0] + sw) = pkd;
            } else {
                int grow = base + row;
                if (grow < N)
                    *(u64*)(Hout + (size_t)grow * 128 + xoff) = pkd;
            }
        }
        if (t < 15) LDS_BARRIER();
    }
}

// ---------------------------------------------------------------------------
__global__ void bn_prep(float* stats, const float* __restrict__ gamma,
                        const float* __restrict__ beta, float invN)
{
    int cidx = threadIdx.x;   // 0..127
    float s = stats[cidx], sq = stats[128 + cidx];
    float mu = s * invN;
    float var = sq * invN - mu * mu;
    float sc = gamma[cidx] * rsqrtf(var + 1e-5f);
    stats[256 + cidx] = sc;
    stats[384 + cidx] = beta[cidx] - mu * sc;
}

// final BN (f32 out, no relu)
__global__ __launch_bounds__(256) void bn_apply_f32(
    const float* __restrict__ X, const float* __restrict__ stats,
    float* __restrict__ Y, int M)
{
    int gid = blockIdx.x * 256 + threadIdx.x;
    int row = gid >> 4;
    int cs  = (gid & 15) * 8;
    if (row >= M) return;
    float4_t a = *(const float4_t*)(X + (size_t)row * 128 + cs);
    float4_t b = *(const float4_t*)(X + (size_t)row * 128 + cs + 4);
    float4_t o1, o2;
#pragma unroll
    for (int j = 0; j < 4; ++j) {
        o1[j] = a[j] * stats[256 + cs + j] + stats[384 + cs + j];
        o2[j] = b[j] * stats[256 + cs + 4 + j] + stats[384 + cs + 4 + j];
    }
    *(float4_t*)(Y + (size_t)row * 128 + cs) = o1;
    *(float4_t*)(Y + (size_t)row * 128 + cs + 4) = o2;
}

// ---------------------------------------------------------------------------
extern "C" void kernel_launch(void* const* d_in, const int* in_sizes, int n_in,
                              void* d_out, int out_size, void* d_ws, size_t ws_size,
                              hipStream_t stream)
{
    const float* in_feat = (const float*)d_in[0];
    const int*   nbr     = (const int*)d_in[1];
    const float* Wih1 = (const float*)d_in[2];
    const float* Whh1 = (const float*)d_in[3];
    const float* bih1 = (const float*)d_in[4];
    const float* bhh1 = (const float*)d_in[5];
    const float* Wself1  = (const float*)d_in[6];
    const float* bself1  = (const float*)d_in[7];
    const float* Wneigh1 = (const float*)d_in[8];
    const float* gamma1  = (const float*)d_in[9];
    const float* beta1   = (const float*)d_in[10];
    const float* Wih2 = (const float*)d_in[11];
    const float* Whh2 = (const float*)d_in[12];
    const float* bih2 = (const float*)d_in[13];
    const float* bhh2 = (const float*)d_in[14];
    const float* Wself2  = (const float*)d_in[15];
    const float* bself2  = (const float*)d_in[16];
    const float* Wneigh2 = (const float*)d_in[17];
    const float* gamma2  = (const float*)d_in[18];
    const float* beta2   = (const float*)d_in[19];

    const int N = in_sizes[0] / 128;

    // Buffer plan (no aliasing hazards):
    //   ws[0 .. N*1024)      : Xih [N,512] bf16   (later reused: P2 [N,128] f32)
    //   ws[N*1024 .. +N*256) : hn  [N,128] bf16
    //   ws[... + 2 KB]       : stats[512] f32
    //   d_out                : P1  [N,128] f32    (final output written last)
    char* ws = (char*)d_ws;
    u16*   Xih   = (u16*)ws;
    float* P2    = (float*)ws;                     // reuses Xih space after lstm2
    u16*   hn    = (u16*)(ws + (size_t)N * 1024);
    float* stats = (float*)(ws + (size_t)N * 1024 + (size_t)N * 256);
    float* P1    = (float*)d_out;

    const int nblk = (N + 63) / 64;
    const float invN = 1.0f / (float)N;
    const int bnblk = (N * 16 + 255) / 256;

    // ---------------- layer 1 ----------------
    gemm_ih<float><<<dim3(nblk, 4), dim3(256), 0, stream>>>(in_feat, Wih1, bih1, bhh1, Xih, stats, N);
    lstm_kernel<<<dim3(nblk), dim3(512), 0, stream>>>(Xih, nbr, Whh1, hn, N);
    gemm_out<float><<<dim3(nblk, 1), dim3(256), 0, stream>>>(hn, Wneigh1, in_feat, Wself1,
                                                             bself1, P1, stats, N);
    bn_prep<<<dim3(1), dim3(128), 0, stream>>>(stats, gamma1, beta1, invN);

    // ---------------- layer 2 (bn+relu fused into consumers of P1) ----------
    gemm_ih_bn<<<dim3(nblk, 4), dim3(256), 0, stream>>>(P1, Wih2, bih2, bhh2, Xih, stats, N);
    lstm_kernel<<<dim3(nblk), dim3(512), 0, stream>>>(Xih, nbr, Whh2, hn, N);
    gemm_out_bn<<<dim3(nblk, 1), dim3(256), 0, stream>>>(hn, Wneigh2, P1, Wself2,
                                                         bself2, P2, stats, N);
    bn_prep<<<dim3(1), dim3(128), 0, stream>>>(stats, gamma2, beta2, invN);
    bn_apply_f32<<<dim3(bnblk), dim3(256), 0, stream>>>(P2, stats, (float*)d_out, N);
}